// Round 8
// baseline (763.420 us; speedup 1.0000x reference)
//
#include <hip/hip_runtime.h>
#include <cstddef>
#include <cstdint>

#define S3 32768  // 32*32*32 spatial positions

typedef short bf16x8 __attribute__((ext_vector_type(8)));   // 8 bf16 in 4 VGPRs
typedef float f32x16 __attribute__((ext_vector_type(16)));

static __device__ inline unsigned short f2bf(float f) {
    unsigned int u = __float_as_uint(f);
    unsigned int r = (u + 0x7FFFu + ((u >> 16) & 1u)) >> 16;  // RNE
    return (unsigned short)r;
}

// unpack 8 bf16 (one uint4) -> 8 fp32
static __device__ inline void bf8_to_f32(uint4 v, float* o) {
    unsigned a[4] = {v.x, v.y, v.z, v.w};
#pragma unroll
    for (int w = 0; w < 4; ++w) {
        o[2 * w]     = __uint_as_float((a[w] & 0xFFFFu) << 16);
        o[2 * w + 1] = __uint_as_float(a[w] & 0xFFFF0000u);
    }
}

// --------- weight transpose: wT[tap][icb][c][kb][chunk(=half*32+ln)][8ic] --
template <int IC, int OC>
__global__ __launch_bounds__(256) void wt_transpose(
    const float* __restrict__ w, unsigned short* __restrict__ wT)
{
    int t = blockIdx.x * 256 + threadIdx.x;  // < 125*IC*OC
    int e = t & 7;
    int chunk = (t >> 3) & 63;
    int kb = (t >> 9) & 1;
    int rest = t >> 10;                       // (tap*ICB + icb)*WOC + c
    int c = rest % (OC / 32); rest /= (OC / 32);
    int icb = rest % (IC / 32);
    int tap = rest / (IC / 32);
    int ln = chunk & 31, half = chunk >> 5;
    int oc = c * 32 + ln;
    int ic = icb * 32 + kb * 16 + half * 8 + e;
    wT[t] = f2bf(w[((size_t)oc * IC + ic) * 125 + tap]);
}

// ---------------- x transpose: xb[b][z][y][x][128 ic] bf16 -----------------
__global__ __launch_bounds__(256) void xb_transpose(
    const float* __restrict__ x, unsigned short* __restrict__ xb)
{
    __shared__ float tile[32][133];
    int zy = blockIdx.x, b = blockIdx.y;
    int t = threadIdx.x, xi = t & 31, ich = t >> 5;
#pragma unroll
    for (int k = 0; k < 16; ++k) {
        int ic = k * 8 + ich;
        tile[xi][ic] = x[(size_t)(b * 128 + ic) * S3 + zy * 32 + xi];
    }
    __syncthreads();
#pragma unroll
    for (int k = 0; k < 2; ++k) {
        int u = t + 256 * k;
        int xx = u >> 4, j = u & 15;
        __align__(16) unsigned short tmp[8];
#pragma unroll
        for (int e = 0; e < 8; ++e) tmp[e] = f2bf(tile[xx][j * 8 + e]);
        *(uint4*)(xb + ((size_t)b * S3 + zy * 32 + xx) * 128 + j * 8) =
            *(const uint4*)tmp;
    }
}

// ---------------- token = mixer_w @ basis ; q = wq[4] @ token --------------
__global__ __launch_bounds__(256) void token_q_kernel(
    const float* __restrict__ basis, const float* __restrict__ mixer,
    const float* __restrict__ wq, float* __restrict__ token,
    float* __restrict__ qbuf)
{
    int s = blockIdx.x * 256 + threadIdx.x;
    float tok[32];
#pragma unroll
    for (int c = 0; c < 32; ++c) tok[c] = 0.f;
#pragma unroll
    for (int r = 0; r < 8; ++r) {
        float bv = basis[r * S3 + s];
#pragma unroll
        for (int c = 0; c < 32; ++c) tok[c] += mixer[c * 8 + r] * bv;
    }
#pragma unroll
    for (int c = 0; c < 32; ++c) token[c * S3 + s] = tok[c];
    const float* wq4 = wq + 4 * 1024;
#pragma unroll
    for (int o = 0; o < 32; ++o) {
        float a = 0.f;
#pragma unroll
        for (int c = 0; c < 32; ++c) a += wq4[o * 32 + c] * tok[c];
        qbuf[o * S3 + s] = a;
    }
}

// -------- attention (row 4 only), two-pass, K/V from xb bf16 (r7) ----------
__global__ __launch_bounds__(256) void attention_kernel(
    const unsigned short* __restrict__ xb, const float* __restrict__ token,
    const float* __restrict__ qbuf, const float* __restrict__ wk,
    const float* __restrict__ wv, const float* __restrict__ alpha_p,
    float* __restrict__ out)
{
    int t = blockIdx.x * 256 + threadIdx.x;
    int s = t & (S3 - 1);
    int b = t >> 15;

    float q[32];
#pragma unroll
    for (int c = 0; c < 32; ++c) q[c] = qbuf[c * S3 + s];

    const unsigned short* xrow = xb + ((size_t)b * S3 + s) * 128;

    const float scale = 0.17677669529663687f;
    float l[5];
#pragma unroll
    for (int j = 0; j < 5; ++j) {
        float xv[32];
        if (j < 4) {
#pragma unroll
            for (int k = 0; k < 4; ++k)
                bf8_to_f32(*(const uint4*)(xrow + j * 32 + k * 8), xv + k * 8);
        } else {
#pragma unroll
            for (int c = 0; c < 32; ++c) xv[c] = token[(size_t)c * S3 + s];
        }
        const float* wkj = wk + j * 1024;
        float acc = 0.f;
#pragma unroll
        for (int o = 0; o < 32; ++o) {
            float kv = 0.f;
#pragma unroll
            for (int c = 0; c < 32; ++c) kv += wkj[o * 32 + c] * xv[c];
            acc += q[o] * kv;
        }
        l[j] = acc * scale;
    }
    float m = l[0];
#pragma unroll
    for (int j = 1; j < 5; ++j) m = fmaxf(m, l[j]);
    float p[5], sum = 0.f;
#pragma unroll
    for (int j = 0; j < 5; ++j) { p[j] = __expf(l[j] - m); sum += p[j]; }
    float inv = alpha_p[0] / sum;

    float ov[32];
#pragma unroll
    for (int o = 0; o < 32; ++o) ov[o] = 0.f;
#pragma unroll
    for (int j = 0; j < 5; ++j) {
        float xv[32];
        if (j < 4) {
#pragma unroll
            for (int k = 0; k < 4; ++k)
                bf8_to_f32(*(const uint4*)(xrow + j * 32 + k * 8), xv + k * 8);
        } else {
#pragma unroll
            for (int c = 0; c < 32; ++c) xv[c] = token[(size_t)c * S3 + s];
        }
        const float* wvj = wv + j * 1024;
        float pj = p[j];
#pragma unroll
        for (int o = 0; o < 32; ++o) {
            float vv = 0.f;
#pragma unroll
            for (int c = 0; c < 32; ++c) vv += wvj[o * 32 + c] * xv[c];
            ov[o] += pj * vv;
        }
    }
#pragma unroll
    for (int o = 0; o < 32; ++o)
        out[((size_t)b * 32 + o) * S3 + s] = ov[o] * inv;
}

// ===== conv1: kb-split (r4 structure) + REGISTER-DIETED staging (NEW) ======
// r4's JT=8 spilled: acc=128 AGPR leaves 128 arch VGPRs; prei[6]=24 +
// bufA/B 40 + brow 48 + addressing ~ 140 > 128 -> scratch (+7MB symmetric
// FETCH/WRITE). Diet: prei[3] only (12 regs) — staging split into two
// 3-chunk phases: issue(h=0)@gp0 -> stage(h=0)+issue(h=1)@gp2 ->
// stage(h=1)@gp4. Everything else = r4's proven-correct ks kernel.
template <int IC, int OC, bool WRITE_H>
__global__ __launch_bounds__(512, 2) void conv_mfma_ks2(
    const unsigned short* __restrict__ xin, const uint4* __restrict__ wTq,
    const float* __restrict__ bias, unsigned short* __restrict__ hout,
    float* __restrict__ fout)
{
    constexpr int ICB = IC / 32, WOC = OC / 32;
    constexpr int JT = (WOC == 2) ? 8 : 4;   // rows per wave (kb-split)
    constexpr int NW = ICB * 5;              // even
    constexpr int NIN = 2880;                // 20 rows * 36 x * 4 chunks
    constexpr int BUF = 20 * 36 * 80;        // 57600 B per buffer
    __shared__ __align__(16) char lds_in[2 * BUF];  // 115.2 KB

    const int tid = threadIdx.x;
    const int wave = tid >> 6, lane = tid & 63;
    const int ln = lane & 31, half = lane >> 5;
    const int kbw = wave & 1;                // K-half owned by this wave
    const int w2 = wave >> 1;                // pair id 0..3
    const int ochalf = (WOC == 2) ? (w2 >> 1) : 0;
    const int wy = (WOC == 2) ? (w2 & 1) : w2;
    const int z = blockIdx.x, ybl = blockIdx.y, b = blockIdx.z;
    const int y0 = ybl * 16;

    const uint4* wTl = wTq + half * 32 + ln;  // lane-fixed chunk offset

    // ---- window-invariant staging geometry (hoisted; 6 chunks) ----
    int  goff[6];   // global offset sans (gz, icb) term
    bool yxok[6];
#pragma unroll
    for (int k = 0; k < 6; ++k) {
        int i = tid + 512 * k;
        int sub = i & 3, cc = i >> 2;
        int x36 = cc % 36, row = cc / 36;
        int gy = y0 - 2 + row, gx = x36 - 2;
        yxok[k] = ((unsigned)gy < 32u) & ((unsigned)gx < 32u);
        goff[k] = (b * 32768 + gy * 32 + gx) * IC + sub * 8;
    }

    f32x16 acc[JT];
#pragma unroll
    for (int j = 0; j < JT; ++j)
#pragma unroll
        for (int e = 0; e < 16; ++e) acc[j][e] = 0.f;

    uint4 prei[3];   // HALF the r4 footprint — chunks in flight: 3

    // chunks 0-4 are always fully active (512*5=2560 < 2880);
    // chunk 5 active iff tid < 320 (2880 - 2560).
    auto issueH = [&](int icb, int dz, int h) {
        int gz = z + dz - 2;
        bool zok = (unsigned)gz < 32u;
        int zoff = gz * (1024 * IC) + icb * 32;
#pragma unroll
        for (int k = 0; k < 3; ++k) {
            int c = h * 3 + k;
            bool a = (c < 5) || (tid < NIN - 2560);
            if (a) {
                uint4 v = {0u, 0u, 0u, 0u};
                if (zok & yxok[c])
                    v = *(const uint4*)(xin + goff[c] + zoff);
                prei[k] = v;
            }
        }
    };

    auto stageH = [&](int buf, int h) {
        char* base = lds_in + buf * BUF;
#pragma unroll
        for (int k = 0; k < 3; ++k) {
            int c = h * 3 + k;
            bool a = (c < 5) || (tid < NIN - 2560);
            if (a) {
                int i = tid + 512 * c;          // loff recomputed (VGPR diet)
                int sub = i & 3, cc = i >> 2;
                int row = cc / 36, x36 = cc - row * 36;
                *(uint4*)(base + row * 2880 + x36 * 80 + sub * 16) = prei[k];
            }
        }
    };

    bf16x8 bufA[5], bufB[5];

    // loads only this wave's kb half: 5 fragments (dy) per call
    auto fillA = [&](bool valid, int icb, int dz, int dx, bf16x8 (&buf)[5]) {
        if (!valid) return;
#pragma unroll
        for (int dy = 0; dy < 5; ++dy) {
            int tap = (dz * 5 + dy) * 5 + dx;
            int f = ((tap * ICB + icb) * WOC + ochalf) * 2 + kbw;
            buf[dy] = *(const bf16x8*)(wTl + (size_t)f * 64);
        }
    };

    // JT+4 ds_read_b128 feed 5*JT MFMAs (own kb only)
    auto compute = [&](const char* base, bf16x8 (&cur)[5], int dx) {
        bf16x8 brow[JT + 4];
#pragma unroll
        for (int r = 0; r < JT + 4; ++r)
            brow[r] = *(const bf16x8*)(base + (JT * wy + r) * 2880 +
                                       (ln + dx) * 80 + kbw * 32 + half * 16);
#pragma unroll
        for (int dy = 0; dy < 5; ++dy)
#pragma unroll
            for (int j = 0; j < JT; ++j)
                acc[j] = __builtin_amdgcn_mfma_f32_32x32x16_bf16(
                    cur[dy], brow[dy + j], acc[j], 0, 0, 0);
    };

    int cur = 0;
    auto window = [&](int w, bf16x8 (&X)[5], bf16x8 (&Y)[5]) {
        int icb = w / 5, dz = w - icb * 5;
        int nw = w + 1;
        int nicb = nw / 5, ndz = nw - nicb * 5;
        bool more = nw < NW;
        const char* rb = lds_in + cur * BUF;

        fillA(true, icb, dz, 1, Y);
        if (more) issueH(nicb, ndz, 0);       // next-window loads, half 0
        compute(rb, X, 0);
        fillA(true, icb, dz, 2, X);
        compute(rb, Y, 1);
        fillA(true, icb, dz, 3, Y);
        if (more) { stageH(cur ^ 1, 0); issueH(nicb, ndz, 1); }
        compute(rb, X, 2);
        fillA(true, icb, dz, 4, X);
        compute(rb, Y, 3);
        fillA(more, nicb, ndz, 0, Y);
        if (more) stageH(cur ^ 1, 1);
        compute(rb, X, 4);
        // one barrier/window: drain only LDS ops; global loads stay in flight
        asm volatile("s_waitcnt lgkmcnt(0)\n\ts_barrier" ::: "memory");
        cur ^= 1;
    };

    // prologue: fill buf0 (both halves), prefetch first A fragments
    issueH(0, 0, 0);
    stageH(0, 0);
    issueH(0, 0, 1);
    stageH(0, 1);
    fillA(true, 0, 0, 0, bufA);
    __syncthreads();

    for (int wp = 0; wp < NW; wp += 2) {
        window(wp, bufA, bufB);
        window(wp + 1, bufB, bufA);
    }

    __syncthreads();
    // ---- cross-wave kb reduction: partner waves (wave^1) sum acc ----
    {
        char* red = lds_in;
#pragma unroll
        for (int rnd = 0; rnd < JT / 4; ++rnd) {
            if (kbw == 1) {
#pragma unroll
                for (int qi = 0; qi < 4; ++qi) {
                    const uint4* src = (const uint4*)&acc[rnd * 4 + qi];
#pragma unroll
                    for (int wd = 0; wd < 4; ++wd)
                        *(uint4*)(red + (w2 * 4 + qi) * 5120 + lane * 80 +
                                  wd * 16) = src[wd];
                }
            }
            __syncthreads();
            if (kbw == 0) {
#pragma unroll
                for (int qi = 0; qi < 4; ++qi) {
#pragma unroll
                    for (int wd = 0; wd < 4; ++wd) {
                        uint4 v = *(const uint4*)(red + (w2 * 4 + qi) * 5120 +
                                                  lane * 80 + wd * 16);
                        acc[rnd * 4 + qi][wd * 4 + 0] += __uint_as_float(v.x);
                        acc[rnd * 4 + qi][wd * 4 + 1] += __uint_as_float(v.y);
                        acc[rnd * 4 + qi][wd * 4 + 2] += __uint_as_float(v.z);
                        acc[rnd * 4 + qi][wd * 4 + 3] += __uint_as_float(v.w);
                    }
                }
            }
            __syncthreads();
        }
    }

    if (WRITE_H) {
#pragma unroll
        for (int j = 0; j < JT; ++j) {
            if (kbw == 0) {
                char* scr = lds_in + wy * (32 * 144);
#pragma unroll
                for (int r = 0; r < 16; ++r) {
                    int ocr = (r & 3) + 8 * (r >> 2) + 4 * half;
                    int oc = ochalf * 32 + ocr;
                    float v = acc[j][r] + bias[oc];
                    v = 0.5f * v * (1.f + erff(v * 0.70710678118654752f));
                    *(unsigned short*)(scr + ln * 144 + oc * 2) = f2bf(v);
                }
            }
            __syncthreads();
            {
                int u = tid;                 // 512 = 2 wy * 32 x * 8 un
                int wyi = u >> 8, rem = u & 255;
                int xx = rem >> 3, un = rem & 7;
                uint4 v = *(const uint4*)(lds_in + wyi * (32 * 144) +
                                          xx * 144 + un * 16);
                int y = y0 + 8 * wyi + j;
                *(uint4*)(hout + ((((size_t)b * 32 + z) * 32 + y) * 32 + xx)
                          * 64 + un * 8) = v;
            }
            __syncthreads();
        }
    } else {
        if (kbw == 0) {
#pragma unroll
            for (int j = 0; j < JT; ++j) {
                int y = y0 + JT * wy + j;
#pragma unroll
                for (int r = 0; r < 16; ++r) {
                    int oc = (r & 3) + 8 * (r >> 2) + 4 * half;
                    size_t o = ((size_t)b * 32 + oc) * S3 + z * 1024 + y * 32 + ln;
                    fout[o] = acc[j][r] + bias[oc] + fout[o];
                }
            }
        }
    }
}

// ============ conv2: round-4/7 kb-split kernel — UNCHANGED (gauge) =========
template <int IC, int OC, bool WRITE_H>
__global__ __launch_bounds__(512, 2) void conv_mfma_ks(
    const unsigned short* __restrict__ xin, const uint4* __restrict__ wTq,
    const float* __restrict__ bias, unsigned short* __restrict__ hout,
    float* __restrict__ fout)
{
    constexpr int ICB = IC / 32, WOC = OC / 32;
    constexpr int JT = (WOC == 2) ? 8 : 4;   // rows per wave (kb-split)
    constexpr int NW = ICB * 5;              // even
    constexpr int NIN = 2880;                // 20 rows * 36 x * 4 chunks
    constexpr int BUF = 20 * 36 * 80;        // 57600 B per buffer
    constexpr int PREI = 6;
    __shared__ __align__(16) char lds_in[2 * BUF];  // 115.2 KB

    const int tid = threadIdx.x;
    const int wave = tid >> 6, lane = tid & 63;
    const int ln = lane & 31, half = lane >> 5;
    const int kbw = wave & 1;                // K-half owned by this wave
    const int w2 = wave >> 1;                // pair id 0..3
    const int ochalf = (WOC == 2) ? (w2 >> 1) : 0;
    const int wy = (WOC == 2) ? (w2 & 1) : w2;
    const int z = blockIdx.x, ybl = blockIdx.y, b = blockIdx.z;
    const int y0 = ybl * 16;

    const uint4* wTl = wTq + half * 32 + ln;  // lane-fixed chunk offset

    // ---- window-invariant staging geometry (hoisted) ----
    int  goff[PREI];   // global offset sans (gz, icb) term
    bool act[PREI], yxok[PREI];
#pragma unroll
    for (int k = 0; k < PREI; ++k) {
        int i = tid + 512 * k;
        act[k] = i < NIN;
        int sub = i & 3, cc = i >> 2;
        int x36 = cc % 36, row = cc / 36;
        int gy = y0 - 2 + row, gx = x36 - 2;
        yxok[k] = ((unsigned)gy < 32u) & ((unsigned)gx < 32u);
        goff[k] = (b * 32768 + gy * 32 + gx) * IC + sub * 8;
    }

    f32x16 acc[JT];
#pragma unroll
    for (int j = 0; j < JT; ++j)
#pragma unroll
        for (int e = 0; e < 16; ++e) acc[j][e] = 0.f;

    uint4 prei[PREI];

    auto issue = [&](int icb, int dz) {
        int gz = z + dz - 2;
        bool zok = (unsigned)gz < 32u;
        int zoff = gz * (1024 * IC) + icb * 32;
#pragma unroll
        for (int k = 0; k < PREI; ++k) {
            if (act[k]) {
                uint4 v = {0u, 0u, 0u, 0u};
                if (zok & yxok[k])
                    v = *(const uint4*)(xin + goff[k] + zoff);
                prei[k] = v;
            }
        }
    };

    auto stage = [&](int buf) {
        char* base = lds_in + buf * BUF;
#pragma unroll
        for (int k = 0; k < PREI; ++k) {
            if (act[k]) {
                int i = tid + 512 * k;          // loff recomputed (VGPR diet)
                int sub = i & 3, cc = i >> 2;
                int row = cc / 36, x36 = cc - row * 36;
                *(uint4*)(base + row * 2880 + x36 * 80 + sub * 16) = prei[k];
            }
        }
    };

    bf16x8 bufA[5], bufB[5];

    // loads only this wave's kb half: 5 fragments (dy) per call
    auto fillA = [&](bool valid, int icb, int dz, int dx, bf16x8 (&buf)[5]) {
        if (!valid) return;
#pragma unroll
        for (int dy = 0; dy < 5; ++dy) {
            int tap = (dz * 5 + dy) * 5 + dx;
            int f = ((tap * ICB + icb) * WOC + ochalf) * 2 + kbw;
            buf[dy] = *(const bf16x8*)(wTl + (size_t)f * 64);
        }
    };

    // JT+4 ds_read_b128 feed 5*JT MFMAs (own kb only)
    auto compute = [&](const char* base, bf16x8 (&cur)[5], int dx) {
        bf16x8 brow[JT + 4];
#pragma unroll
        for (int r = 0; r < JT + 4; ++r)
            brow[r] = *(const bf16x8*)(base + (JT * wy + r) * 2880 +
                                       (ln + dx) * 80 + kbw * 32 + half * 16);
#pragma unroll
        for (int dy = 0; dy < 5; ++dy)
#pragma unroll
            for (int j = 0; j < JT; ++j)
                acc[j] = __builtin_amdgcn_mfma_f32_32x32x16_bf16(
                    cur[dy], brow[dy + j], acc[j], 0, 0, 0);
    };

    int cur = 0;
    auto window = [&](int w, bf16x8 (&X)[5], bf16x8 (&Y)[5]) {
        int icb = w / 5, dz = w - icb * 5;
        int nw = w + 1;
        int nicb = nw / 5, ndz = nw - nicb * 5;
        bool more = nw < NW;
        const char* rb = lds_in + cur * BUF;

        fillA(true, icb, dz, 1, Y);
        if (more) issue(nicb, ndz);         // next-window global loads
        compute(rb, X, 0);
        fillA(true, icb, dz, 2, X);
        compute(rb, Y, 1);
        fillA(true, icb, dz, 3, Y);
        if (more) stage(cur ^ 1);           // overlapped LDS write
        compute(rb, X, 2);
        fillA(true, icb, dz, 4, X);
        compute(rb, Y, 3);
        fillA(more, nicb, ndz, 0, Y);
        compute(rb, X, 4);
        // one barrier/window: drain only LDS ops; global loads stay in flight
        asm volatile("s_waitcnt lgkmcnt(0)\n\ts_barrier" ::: "memory");
        cur ^= 1;
    };

    // prologue: fill buf0, prefetch first A fragments
    issue(0, 0);
    fillA(true, 0, 0, 0, bufA);
    stage(0);
    __syncthreads();

    for (int wp = 0; wp < NW; wp += 2) {
        window(wp, bufA, bufB);
        window(wp + 1, bufB, bufA);
    }

    __syncthreads();
    // ---- cross-wave kb reduction: partner waves (wave^1) sum acc ----
    {
        char* red = lds_in;
#pragma unroll
        for (int rnd = 0; rnd < JT / 4; ++rnd) {
            if (kbw == 1) {
#pragma unroll
                for (int qi = 0; qi < 4; ++qi) {
                    const uint4* src = (const uint4*)&acc[rnd * 4 + qi];
#pragma unroll
                    for (int wd = 0; wd < 4; ++wd)
                        *(uint4*)(red + (w2 * 4 + qi) * 5120 + lane * 80 +
                                  wd * 16) = src[wd];
                }
            }
            __syncthreads();
            if (kbw == 0) {
#pragma unroll
                for (int qi = 0; qi < 4; ++qi) {
#pragma unroll
                    for (int wd = 0; wd < 4; ++wd) {
                        uint4 v = *(const uint4*)(red + (w2 * 4 + qi) * 5120 +
                                                  lane * 80 + wd * 16);
                        acc[rnd * 4 + qi][wd * 4 + 0] += __uint_as_float(v.x);
                        acc[rnd * 4 + qi][wd * 4 + 1] += __uint_as_float(v.y);
                        acc[rnd * 4 + qi][wd * 4 + 2] += __uint_as_float(v.z);
                        acc[rnd * 4 + qi][wd * 4 + 3] += __uint_as_float(v.w);
                    }
                }
            }
            __syncthreads();
        }
    }

    if (WRITE_H) {
#pragma unroll
        for (int j = 0; j < JT; ++j) {
            if (kbw == 0) {
                char* scr = lds_in + wy * (32 * 144);
#pragma unroll
                for (int r = 0; r < 16; ++r) {
                    int ocr = (r & 3) + 8 * (r >> 2) + 4 * half;
                    int oc = ochalf * 32 + ocr;
                    float v = acc[j][r] + bias[oc];
                    v = 0.5f * v * (1.f + erff(v * 0.70710678118654752f));
                    *(unsigned short*)(scr + ln * 144 + oc * 2) = f2bf(v);
                }
            }
            __syncthreads();
            {
                int u = tid;
                int wyi = u >> 8, rem = u & 255;
                int xx = rem >> 3, un = rem & 7;
                uint4 v = *(const uint4*)(lds_in + wyi * (32 * 144) +
                                          xx * 144 + un * 16);
                int y = y0 + 8 * wyi + j;
                *(uint4*)(hout + ((((size_t)b * 32 + z) * 32 + y) * 32 + xx)
                          * 64 + un * 8) = v;
            }
            __syncthreads();
        }
    } else {
        // final: bias + attention (already alpha-scaled in fout) added
        if (kbw == 0) {
#pragma unroll
            for (int j = 0; j < JT; ++j) {
                int y = y0 + JT * wy + j;
#pragma unroll
                for (int r = 0; r < 16; ++r) {
                    int oc = (r & 3) + 8 * (r >> 2) + 4 * half;
                    size_t o = ((size_t)b * 32 + oc) * S3 + z * 1024 + y * 32 + ln;
                    fout[o] = acc[j][r] + bias[oc] + fout[o];
                }
            }
        }
    }
}

// ---------------------------------------------------------------------------
extern "C" void kernel_launch(void* const* d_in, const int* in_sizes, int n_in,
                              void* d_out, int out_size, void* d_ws, size_t ws_size,
                              hipStream_t stream)
{
    const float* x       = (const float*)d_in[0];
    const float* basis   = (const float*)d_in[1];
    const float* mixer   = (const float*)d_in[2];
    const float* wq      = (const float*)d_in[3];
    const float* wk      = (const float*)d_in[4];
    const float* wv      = (const float*)d_in[5];
    const float* conv1_w = (const float*)d_in[6];
    const float* conv1_b = (const float*)d_in[7];
    const float* conv2_w = (const float*)d_in[8];
    const float* conv2_b = (const float*)d_in[9];
    const float* alpha   = (const float*)d_in[10];
    float* out = (float*)d_out;

    char* wsb = (char*)d_ws;
    unsigned short* xb  = (unsigned short*)wsb;               // 32 MiB
    unsigned short* h   = (unsigned short*)(wsb + 33554432);  // 16 MiB
    // token/qbuf alias h: both dead before conv1 writes h (same stream order)
    float* token = (float*)(wsb + 33554432);                  // 4 MiB
    float* qbuf  = (float*)(wsb + 37748736);                  // 4 MiB
    unsigned short* wT1 = (unsigned short*)(wsb + 50331648);  // 2 MiB
    unsigned short* wT2 = (unsigned short*)(wsb + 52379648);  // 0.5 MiB

    wt_transpose<128, 64><<<4000, 256, 0, stream>>>(conv1_w, wT1);
    wt_transpose<64, 32><<<1000, 256, 0, stream>>>(conv2_w, wT2);
    xb_transpose<<<dim3(1024, 4), 256, 0, stream>>>(x, xb);

    token_q_kernel<<<S3 / 256, 256, 0, stream>>>(basis, mixer, wq, token, qbuf);
    attention_kernel<<<512, 256, 0, stream>>>(xb, token, qbuf, wk, wv, alpha,
                                              out);

    conv_mfma_ks2<128, 64, true><<<dim3(32, 2, 4), 512, 0, stream>>>(
        xb, (const uint4*)wT1, conv1_b, h, nullptr);
    conv_mfma_ks<64, 32, false><<<dim3(32, 2, 4), 512, 0, stream>>>(
        h, (const uint4*)wT2, conv2_b, nullptr, out);
}